// Round 1
// baseline (1001.896 us; speedup 1.0000x reference)
//
#include <hip/hip_runtime.h>
#include <hip/hip_bf16.h>

#define WAVE 64

// ---------------- CSR build ----------------

__global__ __launch_bounds__(256) void zero_ints(int* a, int na, int* b, int nb) {
    int i = blockIdx.x * blockDim.x + threadIdx.x;
    int st = gridDim.x * blockDim.x;
    for (int k = i; k < na; k += st) a[k] = 0;
    for (int k = i; k < nb; k += st) b[k] = 0;
}

__global__ __launch_bounds__(256) void hist2(const int* __restrict__ dst_um,
                                             const int* __restrict__ dst_mu,
                                             int* __restrict__ cnt_um,
                                             int* __restrict__ cnt_mu, int E) {
    int i = blockIdx.x * blockDim.x + threadIdx.x;
    int st = gridDim.x * blockDim.x;
    for (; i < E; i += st) {
        atomicAdd(&cnt_um[dst_um[i]], 1);
        atomicAdd(&cnt_mu[dst_mu[i]], 1);
    }
}

#define SCAN_TILE 2048  // 256 threads x 8 elems

__global__ __launch_bounds__(256) void scan_blocks(const int* __restrict__ cnt,
                                                   int* __restrict__ off,
                                                   int* __restrict__ bsum, int n) {
    __shared__ int sdata[256];
    int base = blockIdx.x * SCAN_TILE;
    int t = threadIdx.x;
    int v[8];
    int sum = 0;
#pragma unroll
    for (int i = 0; i < 8; i++) {
        int idx = base + t * 8 + i;
        int c = (idx < n) ? cnt[idx] : 0;
        v[i] = sum;  // exclusive within thread
        sum += c;
    }
    sdata[t] = sum;
    __syncthreads();
    for (int s = 1; s < 256; s <<= 1) {
        int y = (t >= s) ? sdata[t - s] : 0;
        __syncthreads();
        sdata[t] += y;
        __syncthreads();
    }
    int texcl = (t == 0) ? 0 : sdata[t - 1];
#pragma unroll
    for (int i = 0; i < 8; i++) {
        int idx = base + t * 8 + i;
        if (idx < n) off[idx] = texcl + v[i];
    }
    if (t == 0) bsum[blockIdx.x] = sdata[255];
}

__global__ __launch_bounds__(256) void scan_finalize(int* __restrict__ off,
                                                     int* __restrict__ cur,
                                                     const int* __restrict__ bsum,
                                                     int n, int Etotal) {
    __shared__ int s_base;
    int b = blockIdx.x;
    if (threadIdx.x == 0) {
        int acc = 0;
        for (int k = 0; k < b; ++k) acc += bsum[k];
        s_base = acc;
    }
    __syncthreads();
    int base = s_base;
    int start = b * SCAN_TILE;
    for (int i = threadIdx.x; i < SCAN_TILE; i += blockDim.x) {
        int idx = start + i;
        if (idx < n) {
            int o = off[idx] + base;
            off[idx] = o;
            cur[idx] = o;
        }
    }
    if (b == 0 && threadIdx.x == 0) off[n] = Etotal;
}

__global__ __launch_bounds__(256) void fill2(const int* __restrict__ src_um,
                                             const int* __restrict__ dst_um,
                                             const int* __restrict__ src_mu,
                                             const int* __restrict__ dst_mu,
                                             int* __restrict__ cur_um, int* __restrict__ cur_mu,
                                             int* __restrict__ csr_um, int* __restrict__ csr_mu,
                                             int E) {
    int i = blockIdx.x * blockDim.x + threadIdx.x;
    int st = gridDim.x * blockDim.x;
    for (; i < E; i += st) {
        int p = atomicAdd(&cur_um[dst_um[i]], 1);
        csr_um[p] = src_um[i];
        int q = atomicAdd(&cur_mu[dst_mu[i]], 1);
        csr_mu[q] = src_mu[i];
    }
}

// ---------------- segment mean (gather, one wave per dst row) ----------------
// D floats per row; LPE = D/4 lanes per edge (float4 each); GRP = 64/LPE edges/iter.

template <int D>
__global__ __launch_bounds__(256) void agg_mean_v(const int* __restrict__ csr,
                                                  const int* __restrict__ off,
                                                  const float* __restrict__ x,
                                                  float* __restrict__ out, int nrows) {
    constexpr int LPE = D / 4;
    constexpr int GRP = 64 / LPE;
    int wave = (blockIdx.x * blockDim.x + threadIdx.x) >> 6;
    int lane = threadIdx.x & 63;
    int nwaves = (gridDim.x * blockDim.x) >> 6;
    int g = lane / LPE;   // edge slot within iteration
    int cl = lane % LPE;  // column quad
    for (int row = wave; row < nrows; row += nwaves) {
        int s = off[row], e = off[row + 1];
        float4 acc = make_float4(0.f, 0.f, 0.f, 0.f);
        for (int k = s + g; k < e; k += GRP) {
            int idx = csr[k];
            const float4 v = *(const float4*)&x[(long)idx * D + cl * 4];
            acc.x += v.x; acc.y += v.y; acc.z += v.z; acc.w += v.w;
        }
        // combine the GRP partial sums (lanes differing in g, same cl)
        for (int m = LPE; m < 64; m <<= 1) {
            acc.x += __shfl_xor(acc.x, m, 64);
            acc.y += __shfl_xor(acc.y, m, 64);
            acc.z += __shfl_xor(acc.z, m, 64);
            acc.w += __shfl_xor(acc.w, m, 64);
        }
        if (g == 0) {
            float inv = 1.0f / fmaxf((float)(e - s), 1.0f);
            float4 r = make_float4(acc.x * inv, acc.y * inv, acc.z * inv, acc.w * inv);
            *(float4*)&out[(long)row * D + cl * 4] = r;
        }
    }
}

// ---------------- per-node dense: out = act(mean@Wl + b + xd@Wr) ----------------
// Wl: (Dm,64), Wr: (Dd,64) row-major. 16 rows per block, 256 threads.

template <int Dm, int Dd, bool RELU>
__global__ __launch_bounds__(256) void dense_node(const float* __restrict__ mean,
                                                  const float* __restrict__ xd,
                                                  const float* __restrict__ Wl,
                                                  const float* __restrict__ Wr,
                                                  const float* __restrict__ bias,
                                                  float* __restrict__ out, int n) {
    constexpr int H = 64;
    constexpr int ROWS = 16;
    __shared__ float sWl[Dm][H];
    __shared__ float sWr[Dd][H];
    __shared__ float sb[H];
    __shared__ float sm[ROWS][Dm];
    __shared__ float sx[ROWS][Dd];
    int t = threadIdx.x;
    for (int i = t; i < Dm * H; i += 256) sWl[i / H][i % H] = Wl[i];
    for (int i = t; i < Dd * H; i += 256) sWr[i / H][i % H] = Wr[i];
    if (t < H) sb[t] = bias[t];
    int rowbase = blockIdx.x * ROWS;
    for (int i = t; i < ROWS * Dm; i += 256) {
        int r = i / Dm, k = i % Dm;
        int gr = rowbase + r;
        sm[r][k] = (gr < n) ? mean[(long)gr * Dm + k] : 0.f;
    }
    for (int i = t; i < ROWS * Dd; i += 256) {
        int r = i / Dd, k = i % Dd;
        int gr = rowbase + r;
        sx[r][k] = (gr < n) ? xd[(long)gr * Dd + k] : 0.f;
    }
    __syncthreads();
    int j = t & 63;
    int r0 = t >> 6;  // 0..3
    for (int rr = r0; rr < ROWS; rr += 4) {
        int gr = rowbase + rr;
        if (gr >= n) continue;
        float acc = sb[j];
#pragma unroll
        for (int k = 0; k < Dm; ++k) acc += sm[rr][k] * sWl[k][j];
#pragma unroll
        for (int k = 0; k < Dd; ++k) acc += sx[rr][k] * sWr[k][j];
        out[(long)gr * H + j] = RELU ? fmaxf(acc, 0.f) : acc;
    }
}

// ---------------- head ----------------

__global__ __launch_bounds__(256) void head_kernel(const float* __restrict__ z_user,
                                                   const float* __restrict__ z_movie,
                                                   const int* __restrict__ lrow,
                                                   const int* __restrict__ lcol,
                                                   const float* __restrict__ Wlin,
                                                   const float* __restrict__ blin,
                                                   float* __restrict__ out, int B) {
    int wave = (blockIdx.x * blockDim.x + threadIdx.x) >> 6;
    int lane = threadIdx.x & 63;
    int nw = (gridDim.x * blockDim.x) >> 6;
    for (int b = wave; b < B; b += nw) {
        int r = lrow[b], c = lcol[b];
        float zu = z_user[(long)r * 64 + lane];
        float zm = z_movie[(long)c * 64 + lane];
        float p0 = zu * Wlin[lane * 2 + 0] + zm * Wlin[(64 + lane) * 2 + 0];
        float p1 = zu * Wlin[lane * 2 + 1] + zm * Wlin[(64 + lane) * 2 + 1];
        for (int s = 32; s; s >>= 1) {
            p0 += __shfl_xor(p0, s, 64);
            p1 += __shfl_xor(p1, s, 64);
        }
        if (lane == 0) {
            float m = p0 + blin[0];
            float x = p1 + blin[1];
            float sp = fmaxf(x, 0.f) + log1pf(expf(-fabsf(x)));  // softplus, stable
            out[b] = m;
            out[B + b] = sp + 1e-6f;
        }
    }
}

// ---------------- launch ----------------

extern "C" void kernel_launch(void* const* d_in, const int* in_sizes, int n_in,
                              void* d_out, int out_size, void* d_ws, size_t ws_size,
                              hipStream_t stream) {
    const float* x_user  = (const float*)d_in[0];
    const float* x_movie = (const float*)d_in[1];
    const int* src_um = (const int*)d_in[2];
    const int* dst_um = (const int*)d_in[3];
    const int* src_mu = (const int*)d_in[4];
    const int* dst_mu = (const int*)d_in[5];
    const int* lrow = (const int*)d_in[6];
    const int* lcol = (const int*)d_in[7];
    const float* W1_um_l = (const float*)d_in[8];
    const float* b1_um   = (const float*)d_in[9];
    const float* W1_um_r = (const float*)d_in[10];
    const float* W1_mu_l = (const float*)d_in[11];
    const float* b1_mu   = (const float*)d_in[12];
    const float* W1_mu_r = (const float*)d_in[13];
    const float* W2_um_l = (const float*)d_in[14];
    const float* b2_um   = (const float*)d_in[15];
    const float* W2_um_r = (const float*)d_in[16];
    const float* W2_mu_l = (const float*)d_in[17];
    const float* b2_mu   = (const float*)d_in[18];
    const float* W2_mu_r = (const float*)d_in[19];
    const float* W_lin   = (const float*)d_in[20];
    const float* b_lin   = (const float*)d_in[21];
    float* out = (float*)d_out;

    const int E  = in_sizes[2];
    const int B  = in_sizes[6];
    const int NU = in_sizes[0] / 32;   // 100000
    const int NM = in_sizes[1] / 64;   // 20000

    // workspace carve-out (256B aligned)
    char* wsp = (char*)d_ws;
    size_t o = 0;
    auto alloc = [&](size_t bytes) {
        size_t p = o;
        o += (bytes + 255) & ~(size_t)255;
        return (void*)(wsp + p);
    };
    int* cur_um = (int*)alloc((size_t)NM * 4);         // counts then cursors
    int* cur_mu = (int*)alloc((size_t)NU * 4);
    int* off_um = (int*)alloc((size_t)(NM + 1) * 4);
    int* off_mu = (int*)alloc((size_t)(NU + 1) * 4);
    int* bsum_um = (int*)alloc(64 * 4);
    int* bsum_mu = (int*)alloc(64 * 4);
    int* csr_um = (int*)alloc((size_t)E * 4);
    int* csr_mu = (int*)alloc((size_t)E * 4);
    float* A_m = (float*)alloc((size_t)NM * 64 * 4);   // movie mean / z_movie
    float* A_u = (float*)alloc((size_t)NU * 64 * 4);   // user mean / z_user
    float* H_m = (float*)alloc((size_t)NM * 64 * 4);   // h_movie
    float* H_u = (float*)alloc((size_t)NU * 64 * 4);   // h_user
    (void)ws_size;

    const int nb_um = (NM + SCAN_TILE - 1) / SCAN_TILE;
    const int nb_mu = (NU + SCAN_TILE - 1) / SCAN_TILE;

    // 1) CSR build
    zero_ints<<<512, 256, 0, stream>>>(cur_um, NM, cur_mu, NU);
    hist2<<<2048, 256, 0, stream>>>(dst_um, dst_mu, cur_um, cur_mu, E);
    scan_blocks<<<nb_um, 256, 0, stream>>>(cur_um, off_um, bsum_um, NM);
    scan_blocks<<<nb_mu, 256, 0, stream>>>(cur_mu, off_mu, bsum_mu, NU);
    scan_finalize<<<nb_um, 256, 0, stream>>>(off_um, cur_um, bsum_um, NM, E);
    scan_finalize<<<nb_mu, 256, 0, stream>>>(off_mu, cur_mu, bsum_mu, NU, E);
    fill2<<<2048, 256, 0, stream>>>(src_um, dst_um, src_mu, dst_mu,
                                    cur_um, cur_mu, csr_um, csr_mu, E);

    // 2) layer 1
    agg_mean_v<32><<<(NM + 3) / 4, 256, 0, stream>>>(csr_um, off_um, x_user, A_m, NM);
    dense_node<32, 64, true><<<(NM + 15) / 16, 256, 0, stream>>>(A_m, x_movie, W1_um_l, W1_um_r,
                                                                 b1_um, H_m, NM);
    agg_mean_v<64><<<(NU + 3) / 4, 256, 0, stream>>>(csr_mu, off_mu, x_movie, A_u, NU);
    dense_node<64, 32, true><<<(NU + 15) / 16, 256, 0, stream>>>(A_u, x_user, W1_mu_l, W1_mu_r,
                                                                 b1_mu, H_u, NU);

    // 3) layer 2 (z written in-place over the mean buffers; safe: rows staged in LDS)
    agg_mean_v<64><<<(NM + 3) / 4, 256, 0, stream>>>(csr_um, off_um, H_u, A_m, NM);
    dense_node<64, 64, false><<<(NM + 15) / 16, 256, 0, stream>>>(A_m, H_m, W2_um_l, W2_um_r,
                                                                  b2_um, A_m, NM);
    agg_mean_v<64><<<(NU + 3) / 4, 256, 0, stream>>>(csr_mu, off_mu, H_m, A_u, NU);
    dense_node<64, 64, false><<<(NU + 15) / 16, 256, 0, stream>>>(A_u, H_u, W2_mu_l, W2_mu_r,
                                                                  b2_mu, A_u, NU);

    // 4) head
    head_kernel<<<4096, 256, 0, stream>>>(A_u, A_m, lrow, lcol, W_lin, b_lin, out, B);
}